// Round 12
// baseline (7633.881 us; speedup 1.0000x reference)
//
#include <hip/hip_runtime.h>
#include <math.h>

// KMeansGrouping: B=32, N=4096, D=256, K=24, 25 iters.
// Round 12: r11's fused assign+sort+sum kernel with the register-spill fix.
// r11 failed on VGPR_Count=36: bare __launch_bounds__(256) let the allocator
// pick max-occupancy and spill acc[24]+cur[24] to scratch (4th recurrence of
// the 24-accumulator spill). Fix: __launch_bounds__(256,2) (128-VGPR budget,
// 2 blocks/CU = 8 waves/CU) + #pragma unroll on the q-loop (static indexing).
// Zero arithmetic/order changes vs r11 (which passed): scores bit-identical.
// FETCH evidence from r11: phase B's feat re-read is L3-resident (~137MB HBM
// per iter, not 270MB) -> fused floor ~25us/iter.

#define BATCH 32
#define NPTS 4096
#define DIM 256
#define NSLOT 24
#define NITER 25
#define NCH 16
#define CPTS 256 // points per fused block

// ---------------- K0: per-point inverse norm (f64) ----------------
__global__ __launch_bounds__(256) void k_norm(const float* __restrict__ feat,
                                              double* __restrict__ inv_norm) {
  int lane = threadIdx.x & 63;
  int wid = threadIdx.x >> 6;
  int p = blockIdx.x * 4 + wid;
  const float4 v = *(const float4*)(feat + (size_t)p * DIM + lane * 4);
  double s = (double)v.x * v.x + (double)v.y * v.y + (double)v.z * v.z + (double)v.w * v.w;
#pragma unroll
  for (int m = 32; m; m >>= 1) s += __shfl_xor(s, m);
  if (lane == 0) inv_norm[p] = 1.0 / fmax(sqrt(s), 1e-12);
}

__device__ __forceinline__ double block_sum_256(double v, double* red) {
#pragma unroll
  for (int m = 32; m; m >>= 1) v += __shfl_xor(v, m);
  int w = threadIdx.x >> 6;
  if ((threadIdx.x & 63) == 0) red[w] = v;
  __syncthreads();
  return red[0] + red[1] + red[2] + red[3];
}

// ---------------- K0b: initial centers (f64 + f32 [d][k]) + c_sq32 --------
// init_idx = floor(linspace(0, N-1, K)): idx_k = floor(k*4095/23).
__global__ __launch_bounds__(256) void k_init_centers(const float* __restrict__ feat,
                                                      const double* __restrict__ inv_norm,
                                                      double* __restrict__ centers,
                                                      float* __restrict__ cT32,
                                                      float* __restrict__ c_sq32) {
  __shared__ double red[4];
  int t = threadIdx.x, k = blockIdx.x, b = blockIdx.y;
  int idx = (int)((double)k * (NPTS - 1) / (NSLOT - 1));
  double v = (double)feat[((size_t)b * NPTS + idx) * DIM + t] * inv_norm[b * NPTS + idx];
  centers[((size_t)b * NSLOT + k) * DIM + t] = v;
  cT32[((size_t)b * DIM + t) * NSLOT + k] = (float)v;
  double s = block_sum_256(v * v, red);
  if (t == 0) c_sq32[b * NSLOT + k] = (float)s;
}

// ---------------- K0c: tiled transpose feat -> xT[b][d][n] (f32) ----------
__global__ __launch_bounds__(256) void k_transpose(const float* __restrict__ feat,
                                                   float* __restrict__ xT) {
  __shared__ float tile[64][65];
  int ix = threadIdx.x & 63, iy = threadIdx.x >> 6;
  int bx = blockIdx.x, by = blockIdx.y, b = blockIdx.z;
  const float* fb = feat + ((size_t)b * NPTS + bx * 64) * DIM + by * 64;
#pragma unroll
  for (int r = 0; r < 64; r += 4)
    tile[r + iy][ix] = fb[(size_t)(r + iy) * DIM + ix];
  __syncthreads();
  float* xb = xT + ((size_t)b * DIM + by * 64) * NPTS + bx * 64;
#pragma unroll
  for (int r = 0; r < 64; r += 4)
    xb[(size_t)(r + iy) * NPTS + ix] = tile[ix][r + iy];
}

// ---------------- K1: fused assign + sort + cluster-run sums ----------------
template <bool USE_T, bool FINAL>
__global__ __launch_bounds__(256, 2) void k_fused(const float* __restrict__ feat,
                                                  const float* __restrict__ xT,
                                                  const double* __restrict__ inv_norm,
                                                  const float* __restrict__ cT32,
                                                  const float* __restrict__ c_sq32,
                                                  double* __restrict__ psumG,
                                                  int* __restrict__ cntG,
                                                  float* __restrict__ masks) {
  __shared__ double i_lds[CPTS];                   // 2 KB
  __shared__ int a_lds[CPTS];                      // 1 KB
  __shared__ unsigned short list[CPTS];            // 0.5 KB
  __shared__ unsigned char sk_arr[CPTS];           // 0.25 KB
  __shared__ int wcnt[4][NSLOT], goff[4][NSLOT];   // 768 B
  __shared__ int off_lds[NSLOT], tot_lds[NSLOT];   // 192 B
  int ch = blockIdx.x, b = blockIdx.y;
  int t = threadIdx.x;
  int lane = t & 63;
  int w = __builtin_amdgcn_readfirstlane(t >> 6);

  i_lds[t] = inv_norm[b * NPTS + ch * CPTS + t];
  __syncthreads();

  // ---- phase A: f32 scoring, EXACT r8/r10/r11 quarter-D left-fold order ----
  const float* cT = cT32 + (size_t)b * DIM * NSLOT;
  const float* csq = c_sq32 + b * NSLOT;
  float acc[NSLOT], cur[NSLOT];
#pragma unroll
  for (int k = 0; k < NSLOT; ++k) acc[k] = 0.0f;
  const float* xp = USE_T ? (xT + (size_t)b * DIM * NPTS + ch * CPTS + t)
                          : (feat + ((size_t)b * NPTS + ch * CPTS + t) * DIM);
#pragma unroll
  for (int q = 0; q < 4; ++q) { // quarter-D partials, left-folded (= r8)
#pragma unroll
    for (int k = 0; k < NSLOT; ++k) cur[k] = 0.0f;
#pragma unroll
    for (int d0 = q * 64; d0 < q * 64 + 64; d0 += 8) {
      float x[8];
      if (USE_T) {
#pragma unroll
        for (int j = 0; j < 8; ++j) x[j] = xp[(size_t)(d0 + j) * NPTS];
      } else {
        float4 v = *(const float4*)(xp + d0);
        float4 u = *(const float4*)(xp + d0 + 4);
        x[0] = v.x; x[1] = v.y; x[2] = v.z; x[3] = v.w;
        x[4] = u.x; x[5] = u.y; x[6] = u.z; x[7] = u.w;
      }
      const float* cp = cT + d0 * NSLOT; // block-uniform -> s_load
#pragma unroll
      for (int k = 0; k < NSLOT; ++k) {
        float s = cur[k];
#pragma unroll
        for (int j = 0; j < 8; ++j) s = fmaf(x[j], cp[j * NSLOT + k], s);
        cur[k] = s;
      }
    }
#pragma unroll
    for (int k = 0; k < NSLOT; ++k) acc[k] += cur[k];
  }
  float inv = (float)i_lds[t];
  int a = 0;
  float best = 0.0f;
#pragma unroll
  for (int k = 0; k < NSLOT; ++k) {
    float s = csq[k] - 2.0f * (acc[k] * inv);
    if (k == 0) { best = s; }
    else if (s < best) { best = s; a = k; } // strict < = first occurrence
  }

  if (FINAL) { // write masks directly, done
#pragma unroll
    for (int k = 0; k < NSLOT; ++k)
      masks[((size_t)b * NSLOT + k) * NPTS + ch * CPTS + t] = (a == k) ? 1.0f : 0.0f;
    return;
  }
  a_lds[t] = a;
  __syncthreads();

  // ---- counting sort (ballot-prefix, ascending n within cluster) ----
  for (int k = 0; k < NSLOT; ++k) {
    unsigned long long bal = __ballot(a == k);
    if (lane == 0) wcnt[w][k] = __popcll(bal);
  }
  __syncthreads();
  if (t < NSLOT) {
    tot_lds[t] = wcnt[0][t] + wcnt[1][t] + wcnt[2][t] + wcnt[3][t];
  }
  __syncthreads();
  if (t < NSLOT) {
    int off = 0;
    for (int k2 = 0; k2 < t; ++k2) off += tot_lds[k2];
    off_lds[t] = off;
    int base = off;
#pragma unroll
    for (int g = 0; g < 4; ++g) { goff[g][t] = base; base += wcnt[g][t]; }
    cntG[(b * NCH + ch) * NSLOT + t] = tot_lds[t];
  }
  __syncthreads();
  unsigned long long lt = (1ull << lane) - 1ull;
  for (int k = 0; k < NSLOT; ++k) {
    unsigned long long bal = __ballot(a == k);
    if (a == k) {
      int pos = goff[w][k] + __popcll(bal & lt);
      list[pos] = (unsigned short)t;
      sk_arr[pos] = (unsigned char)k;
    }
  }
  __syncthreads();

  // ---- phase B: sorted-run accumulation, thread t = dim t ----
  const float* fb = feat + ((size_t)b * NPTS + ch * CPTS) * DIM + t;
  double* psB = psumG + (size_t)(b * NCH + ch) * NSLOT * DIM + t;
  double racc = 0.0;
  for (int i0 = 0; i0 < CPTS; i0 += 8) {
    int nn[8];
    float x[8];
#pragma unroll
    for (int j = 0; j < 8; ++j)
      nn[j] = __builtin_amdgcn_readfirstlane((int)list[i0 + j]);
#pragma unroll
    for (int j = 0; j < 8; ++j) x[j] = fb[(size_t)nn[j] * DIM]; // 8 rows in flight
#pragma unroll
    for (int j = 0; j < 8; ++j) {
      int i = i0 + j;
      racc += (double)x[j] * i_lds[nn[j]];
      int kcur = __builtin_amdgcn_readfirstlane((int)sk_arr[i]); // uniform
      int knxt = (i < CPTS - 1) ? __builtin_amdgcn_readfirstlane((int)sk_arr[i + 1]) : -1;
      if (kcur != knxt) { // cluster run ends -> single flush
        psB[(size_t)kcur * DIM] = racc;
        racc = 0.0;
      }
    }
  }
  // zero-fill empty clusters (each slot written exactly once per block)
  for (int k = 0; k < NSLOT; ++k)
    if (tot_lds[k] == 0) psB[(size_t)k * DIM] = 0.0;
}

// ---------------- K2: combine 16 chunks -> new centers + cT32 + c_sq ------
__global__ __launch_bounds__(256) void k_upd3(const double* __restrict__ psumG,
                                              const int* __restrict__ cntG,
                                              double* __restrict__ centers,
                                              float* __restrict__ cT32,
                                              float* __restrict__ c_sq32) {
  __shared__ double red[4];
  int t = threadIdx.x, k = blockIdx.x, b = blockIdx.y;
  double s = 0.0; // fixed ascending chunk order (deterministic)
#pragma unroll
  for (int ch = 0; ch < NCH; ++ch)
    s += psumG[((size_t)(b * NCH + ch) * NSLOT + k) * DIM + t];
  int cnt = 0;
#pragma unroll
  for (int ch = 0; ch < NCH; ++ch)
    cnt += cntG[(b * NCH + ch) * NSLOT + k];

  size_t ci = ((size_t)b * NSLOT + k) * DIM + t;
  double nc = (cnt > 0) ? (s / (double)cnt) : centers[ci];
  centers[ci] = nc;
  cT32[((size_t)b * DIM + t) * NSLOT + k] = (float)nc;
  double sq = block_sum_256(nc * nc, red);
  if (t == 0) c_sq32[b * NSLOT + k] = (float)sq;
}

// ---------------- K3: centers output ----------------
__global__ __launch_bounds__(256) void k_copyc(const double* __restrict__ centers,
                                               float* __restrict__ out_centers) {
  int t = threadIdx.x, k = blockIdx.x, b = blockIdx.y;
  size_t i = ((size_t)b * NSLOT + k) * DIM + t;
  out_centers[i] = (float)centers[i];
}

extern "C" void kernel_launch(void* const* d_in, const int* in_sizes, int n_in,
                              void* d_out, int out_size, void* d_ws, size_t ws_size,
                              hipStream_t stream) {
  (void)in_sizes; (void)n_in; (void)out_size;
  const float* feat = (const float*)d_in[0];
  float* out_centers = (float*)d_out;                           // (32,24,256)
  float* out_masks = out_centers + (size_t)BATCH * NSLOT * DIM; // (32,24,4096)

  // workspace: ~29 MB fixed + 134 MB xT tail (optional).
  char* p = (char*)d_ws;
  double* inv_norm = (double*)p; p += (size_t)BATCH * NPTS * 8;              // 1.05 MB
  double* centers  = (double*)p; p += (size_t)BATCH * NSLOT * DIM * 8;       // 1.57 MB
  float* cT32      = (float*)p;  p += (size_t)BATCH * DIM * NSLOT * 4;       // 0.79 MB
  float* c_sq32    = (float*)p;  p += (size_t)BATCH * NSLOT * 4;             // 3 KB
  double* psumG    = (double*)p; p += (size_t)BATCH * NCH * NSLOT * DIM * 8; // 25.2 MB
  int* cntG        = (int*)p;    p += (size_t)BATCH * NCH * NSLOT * 4;       // 49 KB
  float* xT        = (float*)p;
  size_t need_xT = (size_t)(p - (char*)d_ws) + (size_t)BATCH * DIM * NPTS * 4; // ~163 MB
  bool useT = ws_size >= need_xT;

  k_norm<<<BATCH * NPTS / 4, 256, 0, stream>>>(feat, inv_norm);
  k_init_centers<<<dim3(NSLOT, BATCH), 256, 0, stream>>>(feat, inv_norm, centers,
                                                         cT32, c_sq32);
  if (useT)
    k_transpose<<<dim3(NPTS / 64, DIM / 64, BATCH), 256, 0, stream>>>(feat, xT);

  dim3 fg(NCH, BATCH);
  for (int it = 0; it < NITER; ++it) {
    if (useT)
      k_fused<true, false><<<fg, 256, 0, stream>>>(feat, xT, inv_norm, cT32, c_sq32,
                                                   psumG, cntG, out_masks);
    else
      k_fused<false, false><<<fg, 256, 0, stream>>>(feat, xT, inv_norm, cT32, c_sq32,
                                                    psumG, cntG, out_masks);
    k_upd3<<<dim3(NSLOT, BATCH), 256, 0, stream>>>(psumG, cntG, centers, cT32, c_sq32);
  }
  if (useT)
    k_fused<true, true><<<fg, 256, 0, stream>>>(feat, xT, inv_norm, cT32, c_sq32,
                                                psumG, cntG, out_masks);
  else
    k_fused<false, true><<<fg, 256, 0, stream>>>(feat, xT, inv_norm, cT32, c_sq32,
                                                 psumG, cntG, out_masks);
  k_copyc<<<dim3(NSLOT, BATCH), 256, 0, stream>>>(centers, out_centers);
}

// Round 13
// 2362.947 us; speedup vs baseline: 3.2307x; 3.2307x over previous
//
#include <hip/hip_runtime.h>
#include <math.h>

// KMeansGrouping: B=32, N=4096, D=256, K=24, 25 iters.
// Round 13: recomposition from PROVEN-FAST parts only.
//  - k_assign: r8's exact kernel (quarter-D per WAVE, dot[24]=24 VGPR -- the
//    only assignment structure that never spilled; r4/r5/r11/r12 all proved
//    24-acc-per-thread is allocator-hostile). Bit-identical scores to r8.
//  - k_gather (new): r11's verified ballot counting-sort + sorted-run
//    single-f64-accumulator sum, standalone (reads assign from global).
//    Replaces k_cluster4's 24x-redundant scans. No register array > 8.
//  - k_upd3: r11/r12's verified 16-chunk ascending combine + exact counts.
// Sum reassociation-only vs r8 (class passed r4-r12).

#define BATCH 32
#define NPTS 4096
#define DIM 256
#define NSLOT 24
#define NITER 25
#define NCH 16
#define CPTS 256 // points per gather block

// ---------------- K0: per-point inverse norm (f64) ----------------
__global__ __launch_bounds__(256) void k_norm(const float* __restrict__ feat,
                                              double* __restrict__ inv_norm) {
  int lane = threadIdx.x & 63;
  int wid = threadIdx.x >> 6;
  int p = blockIdx.x * 4 + wid;
  const float4 v = *(const float4*)(feat + (size_t)p * DIM + lane * 4);
  double s = (double)v.x * v.x + (double)v.y * v.y + (double)v.z * v.z + (double)v.w * v.w;
#pragma unroll
  for (int m = 32; m; m >>= 1) s += __shfl_xor(s, m);
  if (lane == 0) inv_norm[p] = 1.0 / fmax(sqrt(s), 1e-12);
}

__device__ __forceinline__ double block_sum_256(double v, double* red) {
#pragma unroll
  for (int m = 32; m; m >>= 1) v += __shfl_xor(v, m);
  int w = threadIdx.x >> 6;
  if ((threadIdx.x & 63) == 0) red[w] = v;
  __syncthreads();
  return red[0] + red[1] + red[2] + red[3];
}

// ---------------- K0b: initial centers (f64 + f32 [d][k]) + c_sq32 --------
// init_idx = floor(linspace(0, N-1, K)): idx_k = floor(k*4095/23).
__global__ __launch_bounds__(256) void k_init_centers(const float* __restrict__ feat,
                                                      const double* __restrict__ inv_norm,
                                                      double* __restrict__ centers,
                                                      float* __restrict__ cT32,
                                                      float* __restrict__ c_sq32) {
  __shared__ double red[4];
  int t = threadIdx.x, k = blockIdx.x, b = blockIdx.y;
  int idx = (int)((double)k * (NPTS - 1) / (NSLOT - 1));
  double v = (double)feat[((size_t)b * NPTS + idx) * DIM + t] * inv_norm[b * NPTS + idx];
  centers[((size_t)b * NSLOT + k) * DIM + t] = v;
  cT32[((size_t)b * DIM + t) * NSLOT + k] = (float)v;
  double s = block_sum_256(v * v, red);
  if (t == 0) c_sq32[b * NSLOT + k] = (float)s;
}

// ---------------- K0c: tiled transpose feat -> xT[b][d][n] (f32) ----------
__global__ __launch_bounds__(256) void k_transpose(const float* __restrict__ feat,
                                                   float* __restrict__ xT) {
  __shared__ float tile[64][65];
  int ix = threadIdx.x & 63, iy = threadIdx.x >> 6;
  int bx = blockIdx.x, by = blockIdx.y, b = blockIdx.z;
  const float* fb = feat + ((size_t)b * NPTS + bx * 64) * DIM + by * 64;
#pragma unroll
  for (int r = 0; r < 64; r += 4)
    tile[r + iy][ix] = fb[(size_t)(r + iy) * DIM + ix];
  __syncthreads();
  float* xb = xT + ((size_t)b * DIM + by * 64) * NPTS + bx * 64;
#pragma unroll
  for (int r = 0; r < 64; r += 4)
    xb[(size_t)(r + iy) * NPTS + ix] = tile[ix][r + iy];
}

// ---------------- K1: assignment (f32 scoring), quarter-D per wave --------
// EXACT r8 kernel (proven fast, VGPR-safe, bit-exact scores).
template <bool USE_T>
__global__ __launch_bounds__(256) void k_assign(const float* __restrict__ feat,
                                                const float* __restrict__ xT,
                                                const double* __restrict__ inv_norm,
                                                const float* __restrict__ cT32,
                                                const float* __restrict__ c_sq32,
                                                int* __restrict__ assign) {
  __shared__ float part[3][64][NSLOT + 1]; // 19200 B, odd lane stride
  int lane = threadIdx.x & 63;
  int q = __builtin_amdgcn_readfirstlane(threadIdx.x >> 6);
  int blk = blockIdx.x, b = blockIdx.y;
  int n = blk * 64 + lane;
  const float* cb = cT32 + ((size_t)b * DIM + q * 64) * NSLOT;

  float dot[NSLOT];
#pragma unroll
  for (int k = 0; k < NSLOT; ++k) dot[k] = 0.0f;

  for (int d = 0; d < 64; d += 8) {
    float x[8];
    if (USE_T) {
      const float* xp = xT + ((size_t)b * DIM + q * 64 + d) * NPTS + n;
#pragma unroll
      for (int j = 0; j < 8; ++j) x[j] = xp[(size_t)j * NPTS];
    } else {
      float4 v = *(const float4*)(feat + ((size_t)b * NPTS + n) * DIM + q * 64 + d);
      float4 u = *(const float4*)(feat + ((size_t)b * NPTS + n) * DIM + q * 64 + d + 4);
      x[0] = v.x; x[1] = v.y; x[2] = v.z; x[3] = v.w;
      x[4] = u.x; x[5] = u.y; x[6] = u.z; x[7] = u.w;
    }
    const float* cp = cb + (size_t)d * NSLOT; // wave-uniform -> s_load
#pragma unroll
    for (int k = 0; k < NSLOT; ++k) {
      float s = dot[k];
#pragma unroll
      for (int j = 0; j < 8; ++j) s = fmaf(x[j], cp[j * NSLOT + k], s);
      dot[k] = s;
    }
  }

  if (q) {
#pragma unroll
    for (int k = 0; k < NSLOT; ++k) part[q - 1][lane][k] = dot[k];
  }
  __syncthreads();

  if (q == 0) {
    float inv = (float)inv_norm[b * NPTS + n];
    const float* csq = c_sq32 + b * NSLOT; // uniform -> s_load
    int a = 0;
    float best = 0.0f;
#pragma unroll
    for (int k = 0; k < NSLOT; ++k) {
      float df = dot[k] + part[0][lane][k] + part[1][lane][k] + part[2][lane][k];
      float s = csq[k] - 2.0f * (df * inv);
      if (k == 0) { best = s; }
      else if (s < best) { best = s; a = k; }
    }
    assign[b * NPTS + n] = a;
  }
}

// ---------------- K2: gather = sort + sorted-run cluster sums -------------
// Block (ch, b): 256 points. Counting sort (ballot-prefix, ascending n within
// cluster) in LDS, then thread t = dim t streams the 256 feat rows in sorted
// order (coalesced 1KB rows, 8 in flight), ONE f64 accumulator, flush at run
// boundaries. No register array > 8 -> no spill risk.
__global__ __launch_bounds__(256) void k_gather(const float* __restrict__ feat,
                                                const double* __restrict__ inv_norm,
                                                const int* __restrict__ assign,
                                                double* __restrict__ psumG,
                                                int* __restrict__ cntG) {
  __shared__ double i_lds[CPTS];                  // 2 KB
  __shared__ unsigned short list[CPTS];           // 0.5 KB
  __shared__ unsigned char sk_arr[CPTS];          // 0.25 KB
  __shared__ int wcnt[4][NSLOT], goff[4][NSLOT];  // 768 B
  __shared__ int tot_lds[NSLOT];                  // 96 B
  int ch = blockIdx.x, b = blockIdx.y;
  int t = threadIdx.x;
  int lane = t & 63;
  int w = __builtin_amdgcn_readfirstlane(t >> 6);

  i_lds[t] = inv_norm[b * NPTS + ch * CPTS + t];
  int a = assign[b * NPTS + ch * CPTS + t];

  // ---- counting sort (ballot-prefix, ascending n within cluster) ----
  for (int k = 0; k < NSLOT; ++k) {
    unsigned long long bal = __ballot(a == k);
    if (lane == 0) wcnt[w][k] = __popcll(bal);
  }
  __syncthreads();
  if (t < NSLOT)
    tot_lds[t] = wcnt[0][t] + wcnt[1][t] + wcnt[2][t] + wcnt[3][t];
  __syncthreads();
  if (t < NSLOT) {
    int off = 0;
    for (int k2 = 0; k2 < t; ++k2) off += tot_lds[k2];
    int base = off;
#pragma unroll
    for (int g = 0; g < 4; ++g) { goff[g][t] = base; base += wcnt[g][t]; }
    cntG[(b * NCH + ch) * NSLOT + t] = tot_lds[t];
  }
  __syncthreads();
  unsigned long long lt = (1ull << lane) - 1ull;
  for (int k = 0; k < NSLOT; ++k) {
    unsigned long long bal = __ballot(a == k);
    if (a == k) {
      int pos = goff[w][k] + __popcll(bal & lt);
      list[pos] = (unsigned short)t;
      sk_arr[pos] = (unsigned char)k;
    }
  }
  __syncthreads();

  // ---- sorted-run accumulation, thread t = dim t ----
  const float* fb = feat + ((size_t)b * NPTS + ch * CPTS) * DIM + t;
  double* psB = psumG + (size_t)(b * NCH + ch) * NSLOT * DIM + t;
  double racc = 0.0;
  for (int i0 = 0; i0 < CPTS; i0 += 8) {
    int nn[8];
    float x[8];
#pragma unroll
    for (int j = 0; j < 8; ++j)
      nn[j] = __builtin_amdgcn_readfirstlane((int)list[i0 + j]);
#pragma unroll
    for (int j = 0; j < 8; ++j) x[j] = fb[(size_t)nn[j] * DIM]; // 8 rows in flight
#pragma unroll
    for (int j = 0; j < 8; ++j) {
      int i = i0 + j;
      racc += (double)x[j] * i_lds[nn[j]];
      int kcur = __builtin_amdgcn_readfirstlane((int)sk_arr[i]); // uniform
      int knxt = (i < CPTS - 1) ? __builtin_amdgcn_readfirstlane((int)sk_arr[i + 1]) : -1;
      if (kcur != knxt) { // cluster run ends -> single flush
        psB[(size_t)kcur * DIM] = racc;
        racc = 0.0;
      }
    }
  }
  // zero-fill empty clusters (each slot written exactly once per block)
  for (int k = 0; k < NSLOT; ++k)
    if (tot_lds[k] == 0) psB[(size_t)k * DIM] = 0.0;
}

// ---------------- K3: combine 16 chunks -> new centers + cT32 + c_sq ------
__global__ __launch_bounds__(256) void k_upd3(const double* __restrict__ psumG,
                                              const int* __restrict__ cntG,
                                              double* __restrict__ centers,
                                              float* __restrict__ cT32,
                                              float* __restrict__ c_sq32) {
  __shared__ double red[4];
  int t = threadIdx.x, k = blockIdx.x, b = blockIdx.y;
  double s = 0.0; // fixed ascending chunk order (deterministic)
#pragma unroll
  for (int ch = 0; ch < NCH; ++ch)
    s += psumG[((size_t)(b * NCH + ch) * NSLOT + k) * DIM + t];
  int cnt = 0;
#pragma unroll
  for (int ch = 0; ch < NCH; ++ch)
    cnt += cntG[(b * NCH + ch) * NSLOT + k];

  size_t ci = ((size_t)b * NSLOT + k) * DIM + t;
  double nc = (cnt > 0) ? (s / (double)cnt) : centers[ci];
  centers[ci] = nc;
  cT32[((size_t)b * DIM + t) * NSLOT + k] = (float)nc;
  double sq = block_sum_256(nc * nc, red);
  if (t == 0) c_sq32[b * NSLOT + k] = (float)sq;
}

// ---------------- K4: masks + centers output ----------------
__global__ __launch_bounds__(256) void k_mask(const int* __restrict__ assign,
                                              float* __restrict__ masks) {
  int t = threadIdx.x, nc = blockIdx.x, k = blockIdx.y, b = blockIdx.z;
  int n = nc * 256 + t;
  masks[((size_t)b * NSLOT + k) * NPTS + n] = (assign[b * NPTS + n] == k) ? 1.0f : 0.0f;
}

__global__ __launch_bounds__(256) void k_copyc(const double* __restrict__ centers,
                                               float* __restrict__ out_centers) {
  int t = threadIdx.x, k = blockIdx.x, b = blockIdx.y;
  size_t i = ((size_t)b * NSLOT + k) * DIM + t;
  out_centers[i] = (float)centers[i];
}

extern "C" void kernel_launch(void* const* d_in, const int* in_sizes, int n_in,
                              void* d_out, int out_size, void* d_ws, size_t ws_size,
                              hipStream_t stream) {
  (void)in_sizes; (void)n_in; (void)out_size;
  const float* feat = (const float*)d_in[0];
  float* out_centers = (float*)d_out;                           // (32,24,256)
  float* out_masks = out_centers + (size_t)BATCH * NSLOT * DIM; // (32,24,4096)

  // workspace: ~29 MB fixed + 134 MB xT tail (optional).
  char* p = (char*)d_ws;
  double* inv_norm = (double*)p; p += (size_t)BATCH * NPTS * 8;              // 1.05 MB
  double* centers  = (double*)p; p += (size_t)BATCH * NSLOT * DIM * 8;       // 1.57 MB
  float* cT32      = (float*)p;  p += (size_t)BATCH * DIM * NSLOT * 4;       // 0.79 MB
  float* c_sq32    = (float*)p;  p += (size_t)BATCH * NSLOT * 4;             // 3 KB
  int* assign      = (int*)p;    p += (size_t)BATCH * NPTS * 4;              // 0.52 MB
  double* psumG    = (double*)p; p += (size_t)BATCH * NCH * NSLOT * DIM * 8; // 25.2 MB
  int* cntG        = (int*)p;    p += (size_t)BATCH * NCH * NSLOT * 4;       // 49 KB
  float* xT        = (float*)p;
  size_t need_xT = (size_t)(p - (char*)d_ws) + (size_t)BATCH * DIM * NPTS * 4; // ~163 MB
  bool useT = ws_size >= need_xT;

  k_norm<<<BATCH * NPTS / 4, 256, 0, stream>>>(feat, inv_norm);
  k_init_centers<<<dim3(NSLOT, BATCH), 256, 0, stream>>>(feat, inv_norm, centers,
                                                         cT32, c_sq32);
  if (useT)
    k_transpose<<<dim3(NPTS / 64, DIM / 64, BATCH), 256, 0, stream>>>(feat, xT);

  for (int it = 0; it <= NITER; ++it) {
    if (useT)
      k_assign<true><<<dim3(NPTS / 64, BATCH), 256, 0, stream>>>(feat, xT, inv_norm,
                                                                 cT32, c_sq32, assign);
    else
      k_assign<false><<<dim3(NPTS / 64, BATCH), 256, 0, stream>>>(feat, xT, inv_norm,
                                                                  cT32, c_sq32, assign);
    if (it == NITER) break; // final assignment only
    k_gather<<<dim3(NCH, BATCH), 256, 0, stream>>>(feat, inv_norm, assign, psumG, cntG);
    k_upd3<<<dim3(NSLOT, BATCH), 256, 0, stream>>>(psumG, cntG, centers, cT32, c_sq32);
  }

  k_mask<<<dim3(NPTS / 256, NSLOT, BATCH), 256, 0, stream>>>(assign, out_masks);
  k_copyc<<<dim3(NSLOT, BATCH), 256, 0, stream>>>(centers, out_centers);
}

// Round 14
// 2258.502 us; speedup vs baseline: 3.3801x; 1.0462x over previous
//
#include <hip/hip_runtime.h>
#include <math.h>

// KMeansGrouping: B=32, N=4096, D=256, K=24, 25 iters.
// Round 14: r8's exact pipeline (best known: 1729us) with ONE change: drop the
// xT transpose entirely and use k_assign's feat-row path. Rationale (r11 FETCH
// evidence): xT(134MB)+feat(134MB)=268MB > 256MB L3 -> the two arrays thrash
// each other out of Infinity Cache every iteration, forcing ~134MB/iter from
// HBM. With feat alone the per-iter working set is ~144MB -> fully L3-resident
// after iter 1; plus the transpose's 268MB round-trip (~45us) is deleted.
// The <false> path loads IDENTICAL floats in IDENTICAL FMA order ->
// bit-identical scores to r8 (zero numerical risk). cluster4/upd2 untouched.

#define BATCH 32
#define NPTS 4096
#define DIM 256
#define NSLOT 24
#define NITER 25
#define QPTS 1024 // points per k_cluster4 block

// ---------------- K0: per-point inverse norm (f64) ----------------
__global__ __launch_bounds__(256) void k_norm(const float* __restrict__ feat,
                                              double* __restrict__ inv_norm) {
  int lane = threadIdx.x & 63;
  int wid = threadIdx.x >> 6;
  int p = blockIdx.x * 4 + wid; // one wave per point
  const float4 v = *(const float4*)(feat + (size_t)p * DIM + lane * 4);
  double s = (double)v.x * v.x + (double)v.y * v.y + (double)v.z * v.z + (double)v.w * v.w;
#pragma unroll
  for (int m = 32; m; m >>= 1) s += __shfl_xor(s, m);
  if (lane == 0) inv_norm[p] = 1.0 / fmax(sqrt(s), 1e-12);
}

__device__ __forceinline__ double block_sum_256(double v, double* red) {
#pragma unroll
  for (int m = 32; m; m >>= 1) v += __shfl_xor(v, m);
  int w = threadIdx.x >> 6;
  if ((threadIdx.x & 63) == 0) red[w] = v;
  __syncthreads();
  return red[0] + red[1] + red[2] + red[3];
}

// ---------------- K0b: initial centers (f64 + f32 [d][k]) + c_sq32 --------
// init_idx = floor(linspace(0, N-1, K)): idx_k = floor(k*4095/23).
__global__ __launch_bounds__(256) void k_init_centers(const float* __restrict__ feat,
                                                      const double* __restrict__ inv_norm,
                                                      double* __restrict__ centers,
                                                      float* __restrict__ cT32,
                                                      float* __restrict__ c_sq32) {
  __shared__ double red[4];
  int t = threadIdx.x, k = blockIdx.x, b = blockIdx.y;
  int idx = (int)((double)k * (NPTS - 1) / (NSLOT - 1));
  double v = (double)feat[((size_t)b * NPTS + idx) * DIM + t] * inv_norm[b * NPTS + idx];
  centers[((size_t)b * NSLOT + k) * DIM + t] = v;
  cT32[((size_t)b * DIM + t) * NSLOT + k] = (float)v;
  double s = block_sum_256(v * v, red);
  if (t == 0) c_sq32[b * NSLOT + k] = (float)s;
}

// ---------------- K1: assignment (f32 scoring), quarter-D per wave --------
// r8's kernel, feat-row load path (identical floats, identical FMA order ->
// bit-identical scores to r8's xT path).
__global__ __launch_bounds__(256) void k_assign(const float* __restrict__ feat,
                                                const double* __restrict__ inv_norm,
                                                const float* __restrict__ cT32,
                                                const float* __restrict__ c_sq32,
                                                int* __restrict__ assign) {
  __shared__ float part[3][64][NSLOT + 1]; // 19200 B, odd lane stride
  int lane = threadIdx.x & 63;
  int q = __builtin_amdgcn_readfirstlane(threadIdx.x >> 6);
  int blk = blockIdx.x, b = blockIdx.y;
  int n = blk * 64 + lane;
  const float* cb = cT32 + ((size_t)b * DIM + q * 64) * NSLOT;

  float dot[NSLOT];
#pragma unroll
  for (int k = 0; k < NSLOT; ++k) dot[k] = 0.0f;

  const float* xrow = feat + ((size_t)b * NPTS + n) * DIM + q * 64;
  for (int d = 0; d < 64; d += 8) {
    float4 v = *(const float4*)(xrow + d);
    float4 u = *(const float4*)(xrow + d + 4);
    float x[8];
    x[0] = v.x; x[1] = v.y; x[2] = v.z; x[3] = v.w;
    x[4] = u.x; x[5] = u.y; x[6] = u.z; x[7] = u.w;
    const float* cp = cb + (size_t)d * NSLOT; // wave-uniform -> s_load
#pragma unroll
    for (int k = 0; k < NSLOT; ++k) {
      float s = dot[k];
#pragma unroll
      for (int j = 0; j < 8; ++j) s = fmaf(x[j], cp[j * NSLOT + k], s);
      dot[k] = s;
    }
  }

  if (q) {
#pragma unroll
    for (int k = 0; k < NSLOT; ++k) part[q - 1][lane][k] = dot[k];
  }
  __syncthreads();

  if (q == 0) {
    float inv = (float)inv_norm[b * NPTS + n];
    const float* csq = c_sq32 + b * NSLOT; // uniform -> s_load
    int a = 0;
    float best = 0.0f;
#pragma unroll
    for (int k = 0; k < NSLOT; ++k) {
      float df = dot[k] + part[0][lane][k] + part[1][lane][k] + part[2][lane][k];
      float s = csq[k] - 2.0f * (df * inv);
      if (k == 0) { best = s; }
      else if (s < best) { best = s; a = k; }
    }
    assign[b * NPTS + n] = a;
  }
}

// ---------------- K2: cluster partial sums, x4 point-split (r8) -----------
__global__ __launch_bounds__(256) void k_cluster4(const float* __restrict__ feat,
                                                  const double* __restrict__ inv_norm,
                                                  const int* __restrict__ assign,
                                                  double* __restrict__ psumG,
                                                  int* __restrict__ cntG) {
  __shared__ unsigned short list[QPTS]; // 2 KB
  __shared__ int wtot[4];
  __shared__ double part[4][DIM];       // 8 KB

  int id = blockIdx.x; // ((b*NSLOT)+k)*4+q
  int q = id & 3;
  int r = id >> 2;
  int k = r % NSLOT;
  int b = r / NSLOT;

  int t = threadIdx.x;
  int lane = t & 63;
  int w = __builtin_amdgcn_readfirstlane(t >> 6);

  // ---- phase 1: compaction of this quarter's members (ascending n) ----
  const int* ab = assign + b * NPTS + q * QPTS;
  int base = 0; // block-uniform
  for (int rr = 0; rr < QPTS / 256; ++rr) {
    bool m = (ab[rr * 256 + t] == k);
    unsigned long long bal = __ballot(m);
    int rank = __popcll(bal & ((1ull << lane) - 1ull));
    if (lane == 0) wtot[w] = __popcll(bal);
    __syncthreads();
    int off = base;
#pragma unroll
    for (int w2 = 0; w2 < 3; ++w2)
      if (w2 < w) off += wtot[w2];
    if (m) list[off + rank] = (unsigned short)(rr * 256 + t);
    base += wtot[0] + wtot[1] + wtot[2] + wtot[3];
    __syncthreads();
  }
  int mcount = base;

  // ---- phase 2: striped, 4 rows in flight per wave ----
  const float* fb = feat + ((size_t)b * NPTS + q * QPTS) * DIM + lane * 4;
  const double* ib = inv_norm + b * NPTS + q * QPTS;
  double a0 = 0.0, a1 = 0.0, a2 = 0.0, a3 = 0.0;

  for (int i = w; i < mcount; i += 16) {
    bool h1 = (i + 4) < mcount, h2 = (i + 8) < mcount, h3 = (i + 12) < mcount;
    int n0 = __builtin_amdgcn_readfirstlane((int)list[i]);
    int n1 = __builtin_amdgcn_readfirstlane((int)list[h1 ? i + 4 : i]);
    int n2 = __builtin_amdgcn_readfirstlane((int)list[h2 ? i + 8 : i]);
    int n3 = __builtin_amdgcn_readfirstlane((int)list[h3 ? i + 12 : i]);
    float4 v0 = *(const float4*)(fb + (size_t)n0 * DIM);
    float4 v1 = *(const float4*)(fb + (size_t)n1 * DIM);
    float4 v2 = *(const float4*)(fb + (size_t)n2 * DIM);
    float4 v3 = *(const float4*)(fb + (size_t)n3 * DIM);
    double i0 = ib[n0], i1 = ib[n1], i2 = ib[n2], i3 = ib[n3];
    a0 += (double)v0.x * i0; a1 += (double)v0.y * i0;
    a2 += (double)v0.z * i0; a3 += (double)v0.w * i0;
    if (h1) { a0 += (double)v1.x * i1; a1 += (double)v1.y * i1;
              a2 += (double)v1.z * i1; a3 += (double)v1.w * i1; }
    if (h2) { a0 += (double)v2.x * i2; a1 += (double)v2.y * i2;
              a2 += (double)v2.z * i2; a3 += (double)v2.w * i2; }
    if (h3) { a0 += (double)v3.x * i3; a1 += (double)v3.y * i3;
              a2 += (double)v3.z * i3; a3 += (double)v3.w * i3; }
  }

  part[w][lane * 4 + 0] = a0;
  part[w][lane * 4 + 1] = a1;
  part[w][lane * 4 + 2] = a2;
  part[w][lane * 4 + 3] = a3;
  __syncthreads();

  double s = ((part[0][t] + part[1][t]) + part[2][t]) + part[3][t]; // fixed order
  psumG[(size_t)id * DIM + t] = s;
  if (t == 0) cntG[id] = mcount;
}

// ---------------- K3: combine quarters -> new centers + cT32 + c_sq -------
__global__ __launch_bounds__(256) void k_upd2(const double* __restrict__ psumG,
                                              const int* __restrict__ cntG,
                                              double* __restrict__ centers,
                                              float* __restrict__ cT32,
                                              float* __restrict__ c_sq32) {
  __shared__ double red[4];
  int t = threadIdx.x, k = blockIdx.x, b = blockIdx.y;
  int id = (b * NSLOT + k) * 4;
  const double* p = psumG + (size_t)id * DIM;
  double s = ((p[t] + p[DIM + t]) + p[2 * DIM + t]) + p[3 * DIM + t]; // fixed order
  int cnt = cntG[id] + cntG[id + 1] + cntG[id + 2] + cntG[id + 3];

  size_t ci = ((size_t)b * NSLOT + k) * DIM + t;
  double nc = (cnt > 0) ? (s / (double)cnt) : centers[ci];
  centers[ci] = nc;
  cT32[((size_t)b * DIM + t) * NSLOT + k] = (float)nc;
  double sq = block_sum_256(nc * nc, red);
  if (t == 0) c_sq32[b * NSLOT + k] = (float)sq;
}

// ---------------- K4: masks + centers output ----------------
__global__ __launch_bounds__(256) void k_mask(const int* __restrict__ assign,
                                              float* __restrict__ masks) {
  int t = threadIdx.x, nc = blockIdx.x, k = blockIdx.y, b = blockIdx.z;
  int n = nc * 256 + t;
  masks[((size_t)b * NSLOT + k) * NPTS + n] = (assign[b * NPTS + n] == k) ? 1.0f : 0.0f;
}

__global__ __launch_bounds__(256) void k_copyc(const double* __restrict__ centers,
                                               float* __restrict__ out_centers) {
  int t = threadIdx.x, k = blockIdx.x, b = blockIdx.y;
  size_t i = ((size_t)b * NSLOT + k) * DIM + t;
  out_centers[i] = (float)centers[i];
}

extern "C" void kernel_launch(void* const* d_in, const int* in_sizes, int n_in,
                              void* d_out, int out_size, void* d_ws, size_t ws_size,
                              hipStream_t stream) {
  (void)in_sizes; (void)n_in; (void)out_size; (void)ws_size;
  const float* feat = (const float*)d_in[0];
  float* out_centers = (float*)d_out;                           // (32,24,256)
  float* out_masks = out_centers + (size_t)BATCH * NSLOT * DIM; // (32,24,4096)

  // workspace: ~10.1 MB (no xT).
  char* p = (char*)d_ws;
  double* inv_norm = (double*)p; p += (size_t)BATCH * NPTS * 8;            // 1.05 MB
  double* centers  = (double*)p; p += (size_t)BATCH * NSLOT * DIM * 8;     // 1.57 MB
  float* cT32      = (float*)p;  p += (size_t)BATCH * DIM * NSLOT * 4;     // 0.79 MB
  float* c_sq32    = (float*)p;  p += (size_t)BATCH * NSLOT * 4;           // 3 KB
  int* assign      = (int*)p;    p += (size_t)BATCH * NPTS * 4;            // 0.52 MB
  double* psumG    = (double*)p; p += (size_t)BATCH * NSLOT * 4 * DIM * 8; // 6.3 MB
  int* cntG        = (int*)p;                                              // 12 KB

  k_norm<<<BATCH * NPTS / 4, 256, 0, stream>>>(feat, inv_norm);
  k_init_centers<<<dim3(NSLOT, BATCH), 256, 0, stream>>>(feat, inv_norm, centers,
                                                         cT32, c_sq32);

  for (int it = 0; it <= NITER; ++it) {
    k_assign<<<dim3(NPTS / 64, BATCH), 256, 0, stream>>>(feat, inv_norm,
                                                         cT32, c_sq32, assign);
    if (it == NITER) break; // final assignment only
    k_cluster4<<<NSLOT * BATCH * 4, 256, 0, stream>>>(feat, inv_norm, assign,
                                                      psumG, cntG);
    k_upd2<<<dim3(NSLOT, BATCH), 256, 0, stream>>>(psumG, cntG, centers, cT32, c_sq32);
  }

  k_mask<<<dim3(NPTS / 256, NSLOT, BATCH), 256, 0, stream>>>(assign, out_masks);
  k_copyc<<<dim3(NSLOT, BATCH), 256, 0, stream>>>(centers, out_centers);
}

// Round 15
// 1828.650 us; speedup vs baseline: 4.1746x; 1.2351x over previous
//
#include <hip/hip_runtime.h>
#include <math.h>

// KMeansGrouping: B=32, N=4096, D=256, K=24, 25 iters.
// Round 15: r8's exact pipeline (best known, 1729us) + BATCH-GROUP BLOCKING.
// r11/r14 established: xT(134MB)+feat(134MB)=268MB > 256MB L3 -> sequential
// scans thrash (one full array misses per pass); but assign NEEDS xT's
// coalesced layout (r14: row-major path costs +22us/iter). Fix: batches are
// independent chains -> run the full 25-iter loop for batches 0-15, then
// 16-31. Per-group working set 67+67+state ~ 140MB < 256MB L3 -> per-iter
// HBM ~ 0 after warm-up. Pure reordering of independent work: BIT-IDENTICAL
// outputs to r8. Bonus: final assign writes masks directly (kills k_mask).

#define BATCH 32
#define GB 16     // batches per group
#define NGROUP 2
#define NPTS 4096
#define DIM 256
#define NSLOT 24
#define NITER 25
#define QPTS 1024 // points per k_cluster4 block

// ---------------- K0: per-point inverse norm (f64) ----------------
__global__ __launch_bounds__(256) void k_norm(const float* __restrict__ feat,
                                              double* __restrict__ inv_norm) {
  int lane = threadIdx.x & 63;
  int wid = threadIdx.x >> 6;
  int p = blockIdx.x * 4 + wid; // one wave per point
  const float4 v = *(const float4*)(feat + (size_t)p * DIM + lane * 4);
  double s = (double)v.x * v.x + (double)v.y * v.y + (double)v.z * v.z + (double)v.w * v.w;
#pragma unroll
  for (int m = 32; m; m >>= 1) s += __shfl_xor(s, m);
  if (lane == 0) inv_norm[p] = 1.0 / fmax(sqrt(s), 1e-12);
}

__device__ __forceinline__ double block_sum_256(double v, double* red) {
#pragma unroll
  for (int m = 32; m; m >>= 1) v += __shfl_xor(v, m);
  int w = threadIdx.x >> 6;
  if ((threadIdx.x & 63) == 0) red[w] = v;
  __syncthreads();
  return red[0] + red[1] + red[2] + red[3];
}

// ---------------- K0b: initial centers (f64 + f32 [d][k]) + c_sq32 --------
// init_idx = floor(linspace(0, N-1, K)): idx_k = floor(k*4095/23).
__global__ __launch_bounds__(256) void k_init_centers(const float* __restrict__ feat,
                                                      const double* __restrict__ inv_norm,
                                                      double* __restrict__ centers,
                                                      float* __restrict__ cT32,
                                                      float* __restrict__ c_sq32) {
  __shared__ double red[4];
  int t = threadIdx.x, k = blockIdx.x, b = blockIdx.y;
  int idx = (int)((double)k * (NPTS - 1) / (NSLOT - 1));
  double v = (double)feat[((size_t)b * NPTS + idx) * DIM + t] * inv_norm[b * NPTS + idx];
  centers[((size_t)b * NSLOT + k) * DIM + t] = v;
  cT32[((size_t)b * DIM + t) * NSLOT + k] = (float)v;
  double s = block_sum_256(v * v, red);
  if (t == 0) c_sq32[b * NSLOT + k] = (float)s;
}

// ---------------- K0c: tiled transpose feat -> xT[b][d][n] (f32) ----------
__global__ __launch_bounds__(256) void k_transpose(const float* __restrict__ feat,
                                                   float* __restrict__ xT) {
  __shared__ float tile[64][65];
  int ix = threadIdx.x & 63, iy = threadIdx.x >> 6;
  int bx = blockIdx.x, by = blockIdx.y, b = blockIdx.z;
  const float* fb = feat + ((size_t)b * NPTS + bx * 64) * DIM + by * 64;
#pragma unroll
  for (int r = 0; r < 64; r += 4)
    tile[r + iy][ix] = fb[(size_t)(r + iy) * DIM + ix];
  __syncthreads();
  float* xb = xT + ((size_t)b * DIM + by * 64) * NPTS + bx * 64;
#pragma unroll
  for (int r = 0; r < 64; r += 4)
    xb[(size_t)(r + iy) * NPTS + ix] = tile[ix][r + iy];
}

// ---------------- K1: assignment (f32 scoring), quarter-D per wave --------
// r8's exact kernel (bit-exact scores). b0 = batch-group offset.
// FINAL=true writes masks directly instead of assign.
template <bool USE_T, bool FINAL>
__global__ __launch_bounds__(256) void k_assign(const float* __restrict__ feat,
                                                const float* __restrict__ xT,
                                                const double* __restrict__ inv_norm,
                                                const float* __restrict__ cT32,
                                                const float* __restrict__ c_sq32,
                                                int* __restrict__ assign,
                                                float* __restrict__ masks,
                                                int b0) {
  __shared__ float part[3][64][NSLOT + 1]; // 19200 B, odd lane stride
  int lane = threadIdx.x & 63;
  int q = __builtin_amdgcn_readfirstlane(threadIdx.x >> 6);
  int blk = blockIdx.x, b = blockIdx.y + b0;
  int n = blk * 64 + lane;
  const float* cb = cT32 + ((size_t)b * DIM + q * 64) * NSLOT;

  float dot[NSLOT];
#pragma unroll
  for (int k = 0; k < NSLOT; ++k) dot[k] = 0.0f;

  for (int d = 0; d < 64; d += 8) {
    float x[8];
    if (USE_T) {
      const float* xp = xT + ((size_t)b * DIM + q * 64 + d) * NPTS + n;
#pragma unroll
      for (int j = 0; j < 8; ++j) x[j] = xp[(size_t)j * NPTS];
    } else {
      float4 v = *(const float4*)(feat + ((size_t)b * NPTS + n) * DIM + q * 64 + d);
      float4 u = *(const float4*)(feat + ((size_t)b * NPTS + n) * DIM + q * 64 + d + 4);
      x[0] = v.x; x[1] = v.y; x[2] = v.z; x[3] = v.w;
      x[4] = u.x; x[5] = u.y; x[6] = u.z; x[7] = u.w;
    }
    const float* cp = cb + (size_t)d * NSLOT; // wave-uniform -> s_load
#pragma unroll
    for (int k = 0; k < NSLOT; ++k) {
      float s = dot[k];
#pragma unroll
      for (int j = 0; j < 8; ++j) s = fmaf(x[j], cp[j * NSLOT + k], s);
      dot[k] = s;
    }
  }

  if (q) {
#pragma unroll
    for (int k = 0; k < NSLOT; ++k) part[q - 1][lane][k] = dot[k];
  }
  __syncthreads();

  if (q == 0) {
    float inv = (float)inv_norm[b * NPTS + n];
    const float* csq = c_sq32 + b * NSLOT; // uniform -> s_load
    int a = 0;
    float best = 0.0f;
#pragma unroll
    for (int k = 0; k < NSLOT; ++k) {
      float df = dot[k] + part[0][lane][k] + part[1][lane][k] + part[2][lane][k];
      float s = csq[k] - 2.0f * (df * inv);
      if (k == 0) { best = s; }
      else if (s < best) { best = s; a = k; }
    }
    if (FINAL) {
#pragma unroll
      for (int k = 0; k < NSLOT; ++k)
        masks[((size_t)b * NSLOT + k) * NPTS + n] = (a == k) ? 1.0f : 0.0f;
    } else {
      assign[b * NPTS + n] = a;
    }
  }
}

// ---------------- K2: cluster partial sums, x4 point-split (r8) -----------
__global__ __launch_bounds__(256) void k_cluster4(const float* __restrict__ feat,
                                                  const double* __restrict__ inv_norm,
                                                  const int* __restrict__ assign,
                                                  double* __restrict__ psumG,
                                                  int* __restrict__ cntG,
                                                  int b0) {
  __shared__ unsigned short list[QPTS]; // 2 KB
  __shared__ int wtot[4];
  __shared__ double part[4][DIM];       // 8 KB

  int id = blockIdx.x; // group-local ((b*NSLOT)+k)*4+q
  int q = id & 3;
  int r = id >> 2;
  int k = r % NSLOT;
  int b = r / NSLOT + b0;
  int gid = ((b * NSLOT) + k) * 4 + q; // global psum slot

  int t = threadIdx.x;
  int lane = t & 63;
  int w = __builtin_amdgcn_readfirstlane(t >> 6);

  // ---- phase 1: compaction of this quarter's members (ascending n) ----
  const int* ab = assign + b * NPTS + q * QPTS;
  int base = 0; // block-uniform
  for (int rr = 0; rr < QPTS / 256; ++rr) {
    bool m = (ab[rr * 256 + t] == k);
    unsigned long long bal = __ballot(m);
    int rank = __popcll(bal & ((1ull << lane) - 1ull));
    if (lane == 0) wtot[w] = __popcll(bal);
    __syncthreads();
    int off = base;
#pragma unroll
    for (int w2 = 0; w2 < 3; ++w2)
      if (w2 < w) off += wtot[w2];
    if (m) list[off + rank] = (unsigned short)(rr * 256 + t);
    base += wtot[0] + wtot[1] + wtot[2] + wtot[3];
    __syncthreads();
  }
  int mcount = base;

  // ---- phase 2: striped, 4 rows in flight per wave ----
  const float* fb = feat + ((size_t)b * NPTS + q * QPTS) * DIM + lane * 4;
  const double* ib = inv_norm + b * NPTS + q * QPTS;
  double a0 = 0.0, a1 = 0.0, a2 = 0.0, a3 = 0.0;

  for (int i = w; i < mcount; i += 16) {
    bool h1 = (i + 4) < mcount, h2 = (i + 8) < mcount, h3 = (i + 12) < mcount;
    int n0 = __builtin_amdgcn_readfirstlane((int)list[i]);
    int n1 = __builtin_amdgcn_readfirstlane((int)list[h1 ? i + 4 : i]);
    int n2 = __builtin_amdgcn_readfirstlane((int)list[h2 ? i + 8 : i]);
    int n3 = __builtin_amdgcn_readfirstlane((int)list[h3 ? i + 12 : i]);
    float4 v0 = *(const float4*)(fb + (size_t)n0 * DIM);
    float4 v1 = *(const float4*)(fb + (size_t)n1 * DIM);
    float4 v2 = *(const float4*)(fb + (size_t)n2 * DIM);
    float4 v3 = *(const float4*)(fb + (size_t)n3 * DIM);
    double i0 = ib[n0], i1 = ib[n1], i2 = ib[n2], i3 = ib[n3];
    a0 += (double)v0.x * i0; a1 += (double)v0.y * i0;
    a2 += (double)v0.z * i0; a3 += (double)v0.w * i0;
    if (h1) { a0 += (double)v1.x * i1; a1 += (double)v1.y * i1;
              a2 += (double)v1.z * i1; a3 += (double)v1.w * i1; }
    if (h2) { a0 += (double)v2.x * i2; a1 += (double)v2.y * i2;
              a2 += (double)v2.z * i2; a3 += (double)v2.w * i2; }
    if (h3) { a0 += (double)v3.x * i3; a1 += (double)v3.y * i3;
              a2 += (double)v3.z * i3; a3 += (double)v3.w * i3; }
  }

  part[w][lane * 4 + 0] = a0;
  part[w][lane * 4 + 1] = a1;
  part[w][lane * 4 + 2] = a2;
  part[w][lane * 4 + 3] = a3;
  __syncthreads();

  double s = ((part[0][t] + part[1][t]) + part[2][t]) + part[3][t]; // fixed order
  psumG[(size_t)gid * DIM + t] = s;
  if (t == 0) cntG[gid] = mcount;
}

// ---------------- K3: combine quarters -> new centers + cT32 + c_sq -------
__global__ __launch_bounds__(256) void k_upd2(const double* __restrict__ psumG,
                                              const int* __restrict__ cntG,
                                              double* __restrict__ centers,
                                              float* __restrict__ cT32,
                                              float* __restrict__ c_sq32,
                                              int b0) {
  __shared__ double red[4];
  int t = threadIdx.x, k = blockIdx.x, b = blockIdx.y + b0;
  int id = (b * NSLOT + k) * 4;
  const double* p = psumG + (size_t)id * DIM;
  double s = ((p[t] + p[DIM + t]) + p[2 * DIM + t]) + p[3 * DIM + t]; // fixed order
  int cnt = cntG[id] + cntG[id + 1] + cntG[id + 2] + cntG[id + 3];

  size_t ci = ((size_t)b * NSLOT + k) * DIM + t;
  double nc = (cnt > 0) ? (s / (double)cnt) : centers[ci];
  centers[ci] = nc;
  cT32[((size_t)b * DIM + t) * NSLOT + k] = (float)nc;
  double sq = block_sum_256(nc * nc, red);
  if (t == 0) c_sq32[b * NSLOT + k] = (float)sq;
}

// ---------------- K4: centers output ----------------
__global__ __launch_bounds__(256) void k_copyc(const double* __restrict__ centers,
                                               float* __restrict__ out_centers) {
  int t = threadIdx.x, k = blockIdx.x, b = blockIdx.y;
  size_t i = ((size_t)b * NSLOT + k) * DIM + t;
  out_centers[i] = (float)centers[i];
}

extern "C" void kernel_launch(void* const* d_in, const int* in_sizes, int n_in,
                              void* d_out, int out_size, void* d_ws, size_t ws_size,
                              hipStream_t stream) {
  (void)in_sizes; (void)n_in; (void)out_size;
  const float* feat = (const float*)d_in[0];
  float* out_centers = (float*)d_out;                           // (32,24,256)
  float* out_masks = out_centers + (size_t)BATCH * NSLOT * DIM; // (32,24,4096)

  // workspace: ~10.2 MB fixed + 134 MB xT tail (optional).
  char* p = (char*)d_ws;
  double* inv_norm = (double*)p; p += (size_t)BATCH * NPTS * 8;            // 1.05 MB
  double* centers  = (double*)p; p += (size_t)BATCH * NSLOT * DIM * 8;     // 1.57 MB
  float* cT32      = (float*)p;  p += (size_t)BATCH * DIM * NSLOT * 4;     // 0.79 MB
  float* c_sq32    = (float*)p;  p += (size_t)BATCH * NSLOT * 4;           // 3 KB
  int* assign      = (int*)p;    p += (size_t)BATCH * NPTS * 4;            // 0.52 MB
  double* psumG    = (double*)p; p += (size_t)BATCH * NSLOT * 4 * DIM * 8; // 6.3 MB
  int* cntG        = (int*)p;    p += (size_t)BATCH * NSLOT * 4 * 4;       // 12 KB
  float* xT        = (float*)p;
  size_t need_xT = (size_t)(p - (char*)d_ws) + (size_t)BATCH * DIM * NPTS * 4; // ~144 MB
  bool useT = ws_size >= need_xT;

  k_norm<<<BATCH * NPTS / 4, 256, 0, stream>>>(feat, inv_norm);
  k_init_centers<<<dim3(NSLOT, BATCH), 256, 0, stream>>>(feat, inv_norm, centers,
                                                         cT32, c_sq32);
  if (useT)
    k_transpose<<<dim3(NPTS / 64, DIM / 64, BATCH), 256, 0, stream>>>(feat, xT);

  // Batch-group blocking: full iteration chain per group of 16 batches.
  // Working set/group = 67MB xT + 67MB feat + ~6MB state -> L3-resident.
  for (int g = 0; g < NGROUP; ++g) {
    int b0 = g * GB;
    for (int it = 0; it <= NITER; ++it) {
      bool fin = (it == NITER);
      dim3 ag(NPTS / 64, GB);
      if (useT) {
        if (fin)
          k_assign<true, true><<<ag, 256, 0, stream>>>(feat, xT, inv_norm, cT32,
                                                       c_sq32, assign, out_masks, b0);
        else
          k_assign<true, false><<<ag, 256, 0, stream>>>(feat, xT, inv_norm, cT32,
                                                        c_sq32, assign, out_masks, b0);
      } else {
        if (fin)
          k_assign<false, true><<<ag, 256, 0, stream>>>(feat, xT, inv_norm, cT32,
                                                        c_sq32, assign, out_masks, b0);
        else
          k_assign<false, false><<<ag, 256, 0, stream>>>(feat, xT, inv_norm, cT32,
                                                         c_sq32, assign, out_masks, b0);
      }
      if (fin) break;
      k_cluster4<<<NSLOT * GB * 4, 256, 0, stream>>>(feat, inv_norm, assign,
                                                     psumG, cntG, b0);
      k_upd2<<<dim3(NSLOT, GB), 256, 0, stream>>>(psumG, cntG, centers,
                                                  cT32, c_sq32, b0);
    }
  }

  k_copyc<<<dim3(NSLOT, BATCH), 256, 0, stream>>>(centers, out_centers);
}